// Round 4
// baseline (168.046 us; speedup 1.0000x reference)
//
#include <hip/hip_runtime.h>

typedef __bf16 bf16_t;
typedef __bf16 bf16x8 __attribute__((ext_vector_type(8)));
typedef __bf16 bf16x4 __attribute__((ext_vector_type(4)));
typedef float f32x4 __attribute__((ext_vector_type(4)));

#define HH 96
#define WW 96
#define CC 128
#define HEADS 4
#define HD 32
#define TOK (HH * WW)      // 9216
#define PLANE (TOK * CC)   // 1179648 elements
#define KW 7
#define KK 49

// weight slab offsets (bf16 elements) inside ws
#define W_QKV 0
#define W_PROJ 49152
#define W_FC1 65536
#define W_FC2 131072
#define W_TOT 196608

// fp32 -> bf16x8 (two float4 loads + cvt)
__device__ __forceinline__ bf16x8 cvt8(const float* __restrict__ p) {
    const f32x4 a = *(const f32x4*)p;
    const f32x4 b = *(const f32x4*)(p + 4);
    bf16x8 r;
    r[0] = (bf16_t)a[0]; r[1] = (bf16_t)a[1]; r[2] = (bf16_t)a[2]; r[3] = (bf16_t)a[3];
    r[4] = (bf16_t)b[0]; r[5] = (bf16_t)b[1]; r[6] = (bf16_t)b[2]; r[7] = (bf16_t)b[3];
    return r;
}

// ---------------------------------------------------------------------------
// NT-tile MFMA strip: C[m][n] += sum_k A[m][k]*W[n][k]; A,W at tile origin.
// A-frag: lane holds A[lane&15][(lane>>4)*8+j]; B-frag: W[t*16+(lane&15)][...]
// C/D: reg r -> row (lane>>4)*4+r, col t*16+(lane&15)
// ---------------------------------------------------------------------------
template <int NT>
__device__ __forceinline__ void mmaN(const bf16_t* __restrict__ A, int lda,
                                     const bf16_t* __restrict__ W, int ldb,
                                     int K, f32x4* acc) {
    const int lane = threadIdx.x & 63;
    const bf16_t* ap = A + (lane & 15) * lda + ((lane >> 4) * 8);
    const bf16_t* bp = W + (lane & 15) * ldb + ((lane >> 4) * 8);
    for (int k0 = 0; k0 < K; k0 += 32) {
        bf16x8 a = *(const bf16x8*)(ap + k0);
#pragma unroll
        for (int t = 0; t < NT; t++) {
            bf16x8 b = *(const bf16x8*)(bp + t * 16 * ldb + k0);
            acc[t] = __builtin_amdgcn_mfma_f32_16x16x32_bf16(a, b, acc[t], 0, 0, 0);
        }
    }
}

// K0: convert the 4 fp32 weight matrices to one bf16 slab in ws.
__global__ __launch_bounds__(256) void k_cvt(const float* __restrict__ qkv_w,
                                             const float* __restrict__ proj_w,
                                             const float* __restrict__ fc1_w,
                                             const float* __restrict__ fc2_w,
                                             bf16_t* __restrict__ wb) {
    const int base = (blockIdx.x * 256 + threadIdx.x) * 4;   // 49152 threads x4
    const float* src;
    if (base < W_PROJ)      src = qkv_w + base;
    else if (base < W_FC1)  src = proj_w + (base - W_PROJ);
    else if (base < W_FC2)  src = fc1_w + (base - W_FC1);
    else                    src = fc2_w + (base - W_FC2);
    const f32x4 a = *(const f32x4*)src;
    bf16x4 r;
    r[0] = (bf16_t)a[0]; r[1] = (bf16_t)a[1]; r[2] = (bf16_t)a[2]; r[3] = (bf16_t)a[3];
    *(bf16x4*)(wb + base) = r;
}

// K1: qkv = x @ qkv_w.T + qkv_b. x fp32 (inline cvt); q/k/v bf16 [tok][128].
__global__ __launch_bounds__(256) void k_qkv(const float* __restrict__ x,
                                             const bf16_t* __restrict__ wb,
                                             const float* __restrict__ bias,
                                             bf16_t* __restrict__ q,
                                             bf16_t* __restrict__ k,
                                             bf16_t* __restrict__ v) {
    const int wid = blockIdx.x * 4 + (threadIdx.x >> 6);   // 3456 waves
    const int m0 = (wid / 6) * 16;
    const int n0 = (wid % 6) * 64;
    const int lane = threadIdx.x & 63;
    const float* ap = x + (m0 + (lane & 15)) * CC + ((lane >> 4) * 8);
    const bf16_t* bp = wb + (n0 + (lane & 15)) * CC + ((lane >> 4) * 8);
    f32x4 acc[4] = {};
    for (int k0 = 0; k0 < CC; k0 += 32) {
        bf16x8 a = cvt8(ap + k0);
#pragma unroll
        for (int t = 0; t < 4; t++) {
            bf16x8 b = *(const bf16x8*)(bp + t * 16 * CC + k0);
            acc[t] = __builtin_amdgcn_mfma_f32_16x16x32_bf16(a, b, acc[t], 0, 0, 0);
        }
    }
#pragma unroll
    for (int t = 0; t < 4; t++) {
        const int n = n0 + t * 16 + (lane & 15);
        const float bb = bias[n];
        const int part = n >> 7;           // 0=q 1=k 2=v
        const int c = n & 127;
        bf16_t* dst = (part == 0) ? q : (part == 1) ? k : v;
#pragma unroll
        for (int r = 0; r < 4; r++) {
            const int m = m0 + (lane >> 4) * 4 + r;
            dst[m * CC + c] = (bf16_t)(acc[t][r] + bb);
        }
    }
}

// K2: neighborhood attention; one block/token, one wave/head. qo: q row is
// read only by its own block, then overwritten with the o row (race-free).
__global__ __launch_bounds__(256) void k_na2d(bf16_t* __restrict__ qo,
                                              const bf16_t* __restrict__ k,
                                              const bf16_t* __restrict__ v) {
    const int tok = blockIdx.x;
    const int head = threadIdx.x >> 6;
    const int lane = threadIdx.x & 63;
    const int i = tok / WW, j = tok % WW;
    const int si = min(max(i - KW / 2, 0), HH - KW);
    const int sj = min(max(j - KW / 2, 0), WW - KW);

    float logit = -1e30f;
    int koff = 0;
    if (lane < KK) {
        const int ni = si + lane / KW;
        const int nj = sj + lane % KW;
        koff = (ni * WW + nj) * CC + head * HD;
        const bf16x8* kp = (const bf16x8*)(k + koff);
        const bf16x8* qp = (const bf16x8*)(qo + tok * CC + head * HD);
        float s = 0.f;
#pragma unroll
        for (int d8 = 0; d8 < 4; d8++) {
            bf16x8 qv = qp[d8];
            bf16x8 kv = kp[d8];
#pragma unroll
            for (int e = 0; e < 8; e++) s += (float)qv[e] * (float)kv[e];
        }
        logit = s * 0.17677669529663687f;   // 1/sqrt(32)
    }
    float mx = logit;
#pragma unroll
    for (int off = 32; off; off >>= 1) mx = fmaxf(mx, __shfl_xor(mx, off));
    const float p = (lane < KK) ? __expf(logit - mx) : 0.f;
    float sum = p;
#pragma unroll
    for (int off = 32; off; off >>= 1) sum += __shfl_xor(sum, off);
    const float inv = 1.f / sum;

    const int d = lane & 31;
    float acc = 0.f;
    for (int nb = 0; nb < KK; nb++) {
        const float a = __shfl(p, nb);
        const int off = __shfl(koff, nb);
        acc += a * (float)v[off + d];
    }
    __syncthreads();   // all q reads done before any o write lands (paranoia)
    if (lane < 32) qo[tok * CC + head * HD + d] = (bf16_t)(acc * inv);
}

// K3: x0 = o @ proj_w.T + proj_b  (o bf16 in d_out; x0 bf16 -> dead k plane)
__global__ __launch_bounds__(256) void k_proj(const bf16_t* __restrict__ o,
                                              const bf16_t* __restrict__ wb,
                                              const float* __restrict__ bias,
                                              bf16_t* __restrict__ x0) {
    const int wid = blockIdx.x * 4 + (threadIdx.x >> 6);   // 1152 waves
    const int m0 = (wid / 2) * 16;
    const int n0 = (wid % 2) * 64;
    f32x4 acc[4] = {};
    mmaN<4>(o + m0 * CC, CC, wb + n0 * CC, CC, CC, acc);
    const int lane = threadIdx.x & 63;
#pragma unroll
    for (int t = 0; t < 4; t++) {
        const int n = n0 + t * 16 + (lane & 15);
        const float bb = bias[n];
#pragma unroll
        for (int r = 0; r < 4; r++) {
            const int m = m0 + (lane >> 4) * 4 + r;
            x0[m * CC + n] = (bf16_t)(acc[t][r] + bb);
        }
    }
}

// K4: fused MLP: out = gelu(x0 @ fc1_w.T + fc1_b) @ fc2_w.T + fc2_b.
// 16 rows/block; h1 [16][512] bf16 in LDS (stride 520). out is FP32.
#define H1S 520
__global__ __launch_bounds__(256) void k_mlp(const bf16_t* __restrict__ x0,
                                             const bf16_t* __restrict__ w1,
                                             const float* __restrict__ b1,
                                             const bf16_t* __restrict__ w2,
                                             const float* __restrict__ b2,
                                             float* __restrict__ out) {
    __shared__ __align__(16) bf16_t h1s[16 * H1S];
    const int wv = threadIdx.x >> 6;
    const int lane = threadIdx.x & 63;
    const int m0 = blockIdx.x * 16;

    {   // stage 1: wave wv -> h1 cols [wv*128, wv*128+128)
        f32x4 acc[8] = {};
        mmaN<8>(x0 + m0 * CC, CC, w1 + (wv * 128) * CC, CC, CC, acc);
#pragma unroll
        for (int t = 0; t < 8; t++) {
            const int n = wv * 128 + t * 16 + (lane & 15);
            const float bb = b1[n];
#pragma unroll
            for (int r = 0; r < 4; r++) {
                const int m = (lane >> 4) * 4 + r;
                const float xv = acc[t][r] + bb;
                const float g = 0.5f * xv * (1.f + erff(xv * 0.7071067811865476f));
                h1s[m * H1S + n] = (bf16_t)g;
            }
        }
    }
    __syncthreads();

    {   // stage 2: wave wv -> out cols [wv*32, wv*32+32), K=512 from LDS
        f32x4 acc[2] = {};
        mmaN<2>(h1s, H1S, w2 + (wv * 32) * (4 * CC), 4 * CC, 4 * CC, acc);
#pragma unroll
        for (int t = 0; t < 2; t++) {
            const int n = wv * 32 + t * 16 + (lane & 15);
            const float bb = b2[n];
#pragma unroll
            for (int r = 0; r < 4; r++) {
                const int m = (lane >> 4) * 4 + r;
                out[(m0 + m) * CC + n] = acc[t][r] + bb;
            }
        }
    }
}

extern "C" void kernel_launch(void* const* d_in, const int* in_sizes, int n_in,
                              void* d_out, int out_size, void* d_ws, size_t ws_size,
                              hipStream_t stream) {
    const float* x      = (const float*)d_in[0];
    const float* qkv_w  = (const float*)d_in[1];
    const float* qkv_b  = (const float*)d_in[2];
    const float* proj_w = (const float*)d_in[3];
    const float* proj_b = (const float*)d_in[4];
    const float* fc1_w  = (const float*)d_in[5];
    const float* fc1_b  = (const float*)d_in[6];
    const float* fc2_w  = (const float*)d_in[7];
    const float* fc2_b  = (const float*)d_in[8];

    // d_out (fp32-sized, 4.5 MB) doubles as bf16 scratch for q then o; the
    // final k_mlp overwrites it with the fp32 result.
    bf16_t* qo = (bf16_t*)d_out;
    bf16_t* ws = (bf16_t*)d_ws;
    bf16_t* kb = ws;                  // [9216][128] bf16
    bf16_t* vb = ws + PLANE;          // [9216][128] bf16
    bf16_t* wb = ws + 2 * PLANE;      // 196608 bf16 weight slab
    bf16_t* x0 = kb;                  // k plane dead after attention
    // total ws: 2*PLANE + W_TOT bf16 = 4.9 MB

    k_cvt <<<192,  256, 0, stream>>>(qkv_w, proj_w, fc1_w, fc2_w, wb);
    k_qkv <<<864,  256, 0, stream>>>(x, wb + W_QKV, qkv_b, qo, kb, vb);
    k_na2d<<<TOK,  256, 0, stream>>>(qo, kb, vb);
    k_proj<<<288,  256, 0, stream>>>(qo, wb + W_PROJ, proj_b, x0);
    k_mlp <<<576,  256, 0, stream>>>(x0, wb + W_FC1, fc1_b, wb + W_FC2, fc2_b,
                                     (float*)d_out);
}